// Round 14
// baseline (825.299 us; speedup 1.0000x reference)
//
#include <hip/hip_runtime.h>
#include <hip/hip_bf16.h>
#include <stdint.h>

// CNF step: 4-layer tanh MLP (33->1024->1024->1024->32) forward + exact
// Jacobian trace via 32 forward-mode tangents. B=4096, H=1024, D=32.
// f32 in/out; bf16 MFMA internally.
//
// R14: R13's fused pipeline with the launcher offset bug FIXED (chunk
// pointers were c*NB*32*1024 instead of c*NB*1024; out2 offset c*NB*32
// instead of c*NB -> chunks 1..3 read poison + OOB atomics).
// Fused step s = [jvp2(s-1) || jvp1(s) || t0(s+1)] in ONE dispatch,
// jvp2/jvp1 INTERLEAVED by blockIdx parity so the ~512 co-resident
// blocks are phase-mixed (one family's MFMA covers the other's glds
// drains -- m114 co-schedule). NB=1024, double-buffered T0/T1.
// GEMM core = R12's validated glds/XOR-swizzle 256x128 (0 conflicts,
// MfmaUtil 37%, ~1832 TF per dispatch).

using bf  = __hip_bfloat16;
using bf2 = __hip_bfloat162;
typedef __attribute__((ext_vector_type(8))) short bf16x8;   // 8 bf16 = 4 VGPRs
typedef __attribute__((ext_vector_type(4))) float f32x4;    // C/D frag

__device__ __forceinline__ float b2f(bf x)    { return __bfloat162float(x); }
__device__ __forceinline__ bf    f2b(float x) { return __float2bfloat16(x); }

__device__ __forceinline__ void gld16(const void* g, void* l) {
  __builtin_amdgcn_global_load_lds((const __attribute__((address_space(1))) void*)g,
                                   (__attribute__((address_space(3))) void*)l,
                                   16, 0, 0);
}

// ---------------------------------------------------------------- small bodies
__device__ __forceinline__ void conv_body(int blk, const float* __restrict__ src,
                                          bf* __restrict__ dst, int n4) {
  const int i = blk * 256 + threadIdx.x;
  if (i >= n4) return;
  float4 v = ((const float4*)src)[i];
  bf2* d = (bf2*)(dst + (size_t)i * 4);
  d[0] = __float22bfloat162_rn(make_float2(v.x, v.y));
  d[1] = __float22bfloat162_rn(make_float2(v.z, v.w));
}

__device__ __forceinline__ void w0t_body(int blk, const float* __restrict__ W0,
                                         bf* __restrict__ W0T) {
  const int idx = blk * 256 + threadIdx.x;
  const int i = idx >> 10, q = idx & 1023;
  W0T[idx] = f2b(W0[q * 33 + i]);
}

__device__ __forceinline__ void t0_body(int blk, const bf* __restrict__ h0c,
                                        const bf* __restrict__ W0T,
                                        bf* __restrict__ T0) {
  const int idx = blk * 256 + threadIdx.x;
  const int m = idx >> 6, seg = idx & 63;
  const int b = m >> 5, i = m & 31;
  const bf2* hp = (const bf2*)(h0c + (size_t)b * 1024 + seg * 16);
  const bf2* wp = (const bf2*)(W0T + (size_t)i * 1024 + seg * 16);
  bf2* dp = (bf2*)(T0 + (size_t)m * 1024 + seg * 16);
#pragma unroll
  for (int u = 0; u < 8; ++u) {
    float2 h = __bfloat1622float2(hp[u]);
    float2 w = __bfloat1622float2(wp[u]);
    float2 r;
    r.x = (1.f - h.x * h.x) * w.x;
    r.y = (1.f - h.y * h.y) * w.y;
    dp[u] = __float22bfloat162_rn(r);
  }
}

// ---------------------------------------------------------------- prep
// [0,128): fwd0 | [128,1152): conv W1 | [1152,2176): conv W2
// [2176,2208): conv W3 | [2208,2336): W0T | 2336: zero divv region
__global__ __launch_bounds__(256) void prep_k(const float* __restrict__ z,
                                              const float* __restrict__ tin,
                                              const float* __restrict__ W0,
                                              const float* __restrict__ b0,
                                              const float* __restrict__ W1,
                                              const float* __restrict__ W2,
                                              const float* __restrict__ W3,
                                              bf* __restrict__ h0,
                                              bf* __restrict__ W0T,
                                              bf* __restrict__ W1b,
                                              bf* __restrict__ W2b,
                                              bf* __restrict__ W3b,
                                              float* __restrict__ out2) {
  __shared__ float zs[32 * 33];
  const int f = blockIdx.x, t = threadIdx.x;
  if (f < 128) {  // fwd0: 32 samples/block
    const int s0 = f * 32;
    for (int j = t; j < 1024; j += 256) {
      const int s = j >> 5, k = j & 31;
      zs[s * 33 + k] = z[(size_t)(s0 + s) * 32 + k];
    }
    if (t < 32) zs[t * 33 + 32] = tin[0];
    __syncthreads();
#pragma unroll 1
    for (int rep = 0; rep < 4; ++rep) {
      const int hh = rep * 256 + t;
      const float* wr = W0 + (size_t)hh * 33;
      float wv[33];
#pragma unroll
      for (int k = 0; k < 33; ++k) wv[k] = wr[k];
      const float bv = b0[hh];
#pragma unroll 1
      for (int s = 0; s < 32; ++s) {
        float acc = bv;
#pragma unroll
        for (int k = 0; k < 33; ++k) acc += wv[k] * zs[s * 33 + k];
        h0[(size_t)(s0 + s) * 1024 + hh] = f2b(tanhf(acc));
      }
    }
  } else if (f < 1152) {
    conv_body(f - 128, W1, W1b, 262144);
  } else if (f < 2176) {
    conv_body(f - 1152, W2, W2b, 262144);
  } else if (f < 2208) {
    conv_body(f - 2176, W3, W3b, 8192);
  } else if (f < 2336) {
    w0t_body(f - 2208, W0, W0T);
  } else {
#pragma unroll
    for (int u = 0; u < 16; ++u) out2[u * 256 + t] = 0.f;
  }
}

// ---------------------------------------------------------------- GEMM cores
// glds(16B) staging, global-side XOR swizzle: lane l stages seg
// (l&7)^(l>>3) of row base+(l>>3); LDS[row][s]=global[row][s^(row&7)],
// read at sa=(kk*4+q4)^(r15&7) -> conflict-free, no ds_write instructions.

// 256x128 block, 128x64 wave-tile (8x4 frags), BK=64.
__device__ __forceinline__ void gemm_core256(bf* As, bf* Bs,
                                             const bf* __restrict__ A,
                                             const bf* __restrict__ B,
                                             size_t m0, size_t n0,
                                             f32x4 (&acc)[8][4]) {
  constexpr int K = 1024;
  const int t = threadIdx.x, l = t & 63, w = t >> 6;
  const int wm = w >> 1, wn = w & 1;
  const int r15 = l & 15, q4 = l >> 4, sw = r15 & 7;
  const int lrow = l >> 3, lseg = (l & 7) ^ lrow;

  const bf* asrc[8]; bf* alds[8];
  const bf* bsrc[4]; bf* blds[4];
#pragma unroll
  for (int u = 0; u < 8; ++u) {
    const int row = w * 64 + u * 8 + lrow;
    asrc[u] = A + (m0 + row) * K + lseg * 8;
    alds[u] = As + (size_t)(w * 64 + u * 8) * 64;
  }
#pragma unroll
  for (int u = 0; u < 4; ++u) {
    const int row = w * 32 + u * 8 + lrow;
    bsrc[u] = B + (n0 + row) * K + lseg * 8;
    blds[u] = Bs + (size_t)(w * 32 + u * 8) * 64;
  }

#pragma unroll 1
  for (int k0 = 0; k0 < K; k0 += 64) {
#pragma unroll
    for (int u = 0; u < 8; ++u) gld16(asrc[u] + k0, alds[u]);
#pragma unroll
    for (int u = 0; u < 4; ++u) gld16(bsrc[u] + k0, blds[u]);
    __syncthreads();
#pragma unroll
    for (int kk = 0; kk < 2; ++kk) {
      const int sa = (kk * 4 + q4) ^ sw;
      bf16x8 af[8], bfr[4];
#pragma unroll
      for (int i = 0; i < 8; ++i)
        af[i] = *(const bf16x8*)(As + (wm * 128 + i * 16 + r15) * 64 + sa * 8);
#pragma unroll
      for (int j = 0; j < 4; ++j)
        bfr[j] = *(const bf16x8*)(Bs + (wn * 64 + j * 16 + r15) * 64 + sa * 8);
#pragma unroll
      for (int mi = 0; mi < 8; ++mi)
#pragma unroll
        for (int ni = 0; ni < 4; ++ni)
          acc[mi][ni] = __builtin_amdgcn_mfma_f32_16x16x32_bf16(af[mi], bfr[ni], acc[mi][ni], 0, 0, 0);
    }
    __syncthreads();
  }
}

// 128x128 block, 64x64 wave-tile (4x4 frags), BK=64 (fwd: 256 blocks).
__device__ __forceinline__ void gemm_core128(bf* As, bf* Bs,
                                             const bf* __restrict__ A,
                                             const bf* __restrict__ B,
                                             size_t m0, size_t n0,
                                             f32x4 (&acc)[4][4]) {
  constexpr int K = 1024;
  const int t = threadIdx.x, l = t & 63, w = t >> 6;
  const int wm = w >> 1, wn = w & 1;
  const int r15 = l & 15, q4 = l >> 4, sw = r15 & 7;
  const int lrow = l >> 3, lseg = (l & 7) ^ lrow;

  const bf* asrc[4]; bf* alds[4];
  const bf* bsrc[4]; bf* blds[4];
#pragma unroll
  for (int u = 0; u < 4; ++u) {
    const int row = w * 32 + u * 8 + lrow;
    asrc[u] = A + (m0 + row) * K + lseg * 8;
    alds[u] = As + (size_t)(w * 32 + u * 8) * 64;
    bsrc[u] = B + (n0 + row) * K + lseg * 8;
    blds[u] = Bs + (size_t)(w * 32 + u * 8) * 64;
  }

#pragma unroll 1
  for (int k0 = 0; k0 < K; k0 += 64) {
#pragma unroll
    for (int u = 0; u < 4; ++u) { gld16(asrc[u] + k0, alds[u]); gld16(bsrc[u] + k0, blds[u]); }
    __syncthreads();
#pragma unroll
    for (int kk = 0; kk < 2; ++kk) {
      const int sa = (kk * 4 + q4) ^ sw;
      bf16x8 af[4], bfr[4];
#pragma unroll
      for (int i = 0; i < 4; ++i) {
        af[i]  = *(const bf16x8*)(As + (wm * 64 + i * 16 + r15) * 64 + sa * 8);
        bfr[i] = *(const bf16x8*)(Bs + (wn * 64 + i * 16 + r15) * 64 + sa * 8);
      }
#pragma unroll
      for (int mi = 0; mi < 4; ++mi)
#pragma unroll
        for (int ni = 0; ni < 4; ++ni)
          acc[mi][ni] = __builtin_amdgcn_mfma_f32_16x16x32_bf16(af[mi], bfr[ni], acc[mi][ni], 0, 0, 0);
    }
    __syncthreads();
  }
}

// ---------------------------------------------------------------- fwd GEMM
__global__ __launch_bounds__(256, 2) void gemm_fwd(const bf* __restrict__ A,
                                                   const bf* __restrict__ W,
                                                   const float* __restrict__ bias,
                                                   bf* __restrict__ H) {
  constexpr int N = 1024;
  __shared__ __align__(16) bf As[128 * 64];
  __shared__ __align__(16) bf Bs[128 * 64];
  const int t = threadIdx.x, l = t & 63, w = t >> 6;
  const int wm = w >> 1, wn = w & 1;
  const int f = blockIdx.x;
  const int n_t = (f >> 3) & 7, m_t = (f & 7) + 8 * (f >> 6);
  const size_t m0 = (size_t)m_t * 128, n0 = (size_t)n_t * 128;
  const int r15 = l & 15, q4 = l >> 4;
  f32x4 acc[4][4] = {};
  gemm_core128(As, Bs, A, W, m0, n0, acc);
#pragma unroll
  for (int ni = 0; ni < 4; ++ni) {
    const int n = (int)n0 + wn * 64 + ni * 16 + r15;
    const float bv = bias[n];
#pragma unroll
    for (int mi = 0; mi < 4; ++mi)
#pragma unroll
      for (int r = 0; r < 4; ++r) {
        const size_t m = m0 + wm * 64 + mi * 16 + q4 * 4 + r;
        H[m * N + n] = f2b(tanhf(acc[mi][ni][r] + bv));
      }
  }
}

// ---------------------------------------------------------------- fwd3 (out)
__global__ __launch_bounds__(256) void fwd3_k(const bf* __restrict__ h2,
                                              const bf* __restrict__ W3b,
                                              const float* __restrict__ b3,
                                              float* __restrict__ out) {
  __shared__ __align__(16) bf hs[8 * 1024];
  const int t = threadIdx.x;
  const size_t bb = (size_t)blockIdx.x * 8;
  const uint4* src = (const uint4*)(h2 + bb * 1024);
  uint4* dv = (uint4*)hs;
#pragma unroll
  for (int j = 0; j < 4; ++j) dv[j * 256 + t] = src[j * 256 + t];
  __syncthreads();
  const int i = t & 31, bl = t >> 5;
  const bf2* hr = (const bf2*)(hs + bl * 1024);
  const bf2* wr = (const bf2*)(W3b + (size_t)i * 1024);
  float s = 0.f;
#pragma unroll 8
  for (int k2 = 0; k2 < 512; ++k2) {
    float2 a = __bfloat1622float2(hr[k2]);
    float2 c = __bfloat1622float2(wr[k2]);
    s += a.x * c.x + a.y * c.y;
  }
  out[(bb + bl) * 32 + i] = s + b3[i];
}

// ---------------------------------------------------------------- t0 (chunk 0)
__global__ __launch_bounds__(256) void t0_k(const bf* __restrict__ h0c,
                                            const bf* __restrict__ W0T,
                                            bf* __restrict__ T0) {
  t0_body(blockIdx.x, h0c, W0T, T0);
}

// ---------------------------------------------------------------- fused jvp step
// GEMM families interleaved by parity when n2==n1; t0 blocks trail.
__global__ __launch_bounds__(256, 2) void jvp_step_k(
    const bf* __restrict__ T1p, const bf* __restrict__ h2p,   // jvp2 inputs
    float* __restrict__ out2p,
    const bf* __restrict__ T0c, const bf* __restrict__ h1c,   // jvp1 inputs
    bf* __restrict__ T1c,
    const bf* __restrict__ h0n, bf* __restrict__ T0n,         // t0 inputs
    const bf* __restrict__ W1b, const bf* __restrict__ W2b,
    const bf* __restrict__ W3b, const bf* __restrict__ W0T,
    int n2, int n1) {
  __shared__ __align__(16) bf smem[24576];  // 48 KB
  const int f = blockIdx.x;
  const int t = threadIdx.x, l = t & 63, w = t >> 6;
  const int wm = w >> 1, wn = w & 1;
  const int r15 = l & 15, q4 = l >> 4;

  if (f >= n2 + n1) {  // ---- t0(c+1)
    t0_body(f - n2 - n1, h0n, W0T, T0n);
    return;
  }
  // family select: interleave jvp2/jvp1 by parity when both present
  int ff, fam;
  if (n2 > 0 && n1 > 0) { ff = f >> 1; fam = f & 1; }       // n2==n1 here
  else if (n2 > 0)      { ff = f; fam = 0; }
  else                  { ff = f; fam = 1; }
  const int n_t = (ff >> 3) & 7, m_t = (ff & 7) + 8 * (ff >> 6);
  const size_t m0 = (size_t)m_t * 256, n0 = (size_t)n_t * 128;

  if (fam == 0) {  // ---- jvp2(c-1): trace atomics
    f32x4 acc[8][4] = {};
    gemm_core256(smem, smem + 16384, T1p, W2b, m0, n0, acc);
    const int bbase = (int)((m0 + wm * 128) >> 5);
    float part[4] = {0.f, 0.f, 0.f, 0.f};
#pragma unroll
    for (int ni = 0; ni < 4; ++ni) {
      const int n = (int)n0 + wn * 64 + ni * 16 + r15;  // = p
      float a2v[4];
#pragma unroll
      for (int s = 0; s < 4; ++s) {
        const float hv = b2f(h2p[(size_t)(bbase + s) * 1024 + n]);
        a2v[s] = 1.f - hv * hv;
      }
#pragma unroll
      for (int mi = 0; mi < 8; ++mi) {
        const int isel = mi >> 1;
#pragma unroll
        for (int r = 0; r < 4; ++r) {
          const int mm = wm * 128 + mi * 16 + q4 * 4 + r;  // i = mm & 31
          part[isel] += b2f(W3b[(size_t)(mm & 31) * 1024 + n]) * a2v[isel] * acc[mi][ni][r];
        }
      }
    }
#pragma unroll
    for (int off2 = 32; off2 > 0; off2 >>= 1) {
#pragma unroll
      for (int s = 0; s < 4; ++s) part[s] += __shfl_down(part[s], off2);
    }
    if (l == 0) {
#pragma unroll
      for (int s = 0; s < 4; ++s) atomicAdd(out2p + bbase + s, -part[s]);
    }
  } else {  // ---- jvp1(c): T1 = diag(1-h1^2)(T0 @ W1^T)
    f32x4 acc[8][4] = {};
    gemm_core256(smem, smem + 16384, T0c, W1b, m0, n0, acc);
    const int bbase = (int)((m0 + wm * 128) >> 5);
#pragma unroll
    for (int ni = 0; ni < 4; ++ni) {
      const int n = (int)n0 + wn * 64 + ni * 16 + r15;
      float a1v[4];
#pragma unroll
      for (int s = 0; s < 4; ++s) {
        const float hv = b2f(h1c[(size_t)(bbase + s) * 1024 + n]);
        a1v[s] = 1.f - hv * hv;
      }
#pragma unroll
      for (int mi = 0; mi < 8; ++mi)
#pragma unroll
        for (int r = 0; r < 4; ++r) {
          const size_t m = m0 + wm * 128 + mi * 16 + q4 * 4 + r;
          T1c[m * 1024 + n] = f2b(a1v[mi >> 1] * acc[mi][ni][r]);
        }
    }
  }
}

// ================================================================ launch
extern "C" void kernel_launch(void* const* d_in, const int* in_sizes, int n_in,
                              void* d_out, int out_size, void* d_ws, size_t ws_size,
                              hipStream_t stream) {
  const float* tin = (const float*)d_in[0];
  const float* z   = (const float*)d_in[1];
  const float* W0  = (const float*)d_in[2];
  const float* b0  = (const float*)d_in[3];
  const float* W1  = (const float*)d_in[4];
  const float* b1  = (const float*)d_in[5];
  const float* W2  = (const float*)d_in[6];
  const float* b2  = (const float*)d_in[7];
  const float* W3  = (const float*)d_in[8];
  const float* b3  = (const float*)d_in[9];
  float* out = (float*)d_out;
  float* out2 = out + 131072;  // divv region, zeroed by prep
  (void)in_sizes; (void)n_in; (void)out_size;

  char* ws = (char*)d_ws;
  size_t off = 0;
  auto take = [&](size_t bytes) {
    char* p = ws + off;
    off = (off + bytes + 255) & ~(size_t)255;
    return p;
  };
  bf* h0   = (bf*)take((size_t)4096 * 1024 * 2);   // 8 MB
  bf* h1   = (bf*)take((size_t)4096 * 1024 * 2);   // 8 MB
  bf* h2   = (bf*)take((size_t)4096 * 1024 * 2);   // 8 MB
  bf* W0T  = (bf*)take((size_t)32 * 1024 * 2);     // 64 KB
  bf* W1b  = (bf*)take((size_t)1024 * 1024 * 2);   // 2 MB
  bf* W2b  = (bf*)take((size_t)1024 * 1024 * 2);   // 2 MB
  bf* W3b  = (bf*)take((size_t)32 * 1024 * 2);     // 64 KB
  // double-buffered T0/T1 chunks: 4 * NB*32*1024*2 bytes
  const size_t avail = (ws_size > off) ? (ws_size - off) : 0;
  int NB = 1024;
  while (NB > 256 && 4 * (size_t)NB * 65536 > avail) NB >>= 1;
  bf* T0a = (bf*)take((size_t)NB * 65536);
  bf* T0b = (bf*)take((size_t)NB * 65536);
  bf* T1a = (bf*)take((size_t)NB * 65536);
  bf* T1b = (bf*)take((size_t)NB * 65536);
  bf* T0buf[2] = {T0a, T0b};
  bf* T1buf[2] = {T1a, T1b};
  const int nchunk = 4096 / NB;

  prep_k<<<dim3(2337), dim3(256), 0, stream>>>(z, tin, W0, b0, W1, W2, W3,
                                               h0, W0T, W1b, W2b, W3b, out2);
  gemm_fwd<<<dim3(256), dim3(256), 0, stream>>>(h0, W1b, b1, h1);
  gemm_fwd<<<dim3(256), dim3(256), 0, stream>>>(h1, W2b, b2, h2);
  fwd3_k<<<dim3(512), dim3(256), 0, stream>>>(h2, W3b, b3, out);
  t0_k<<<dim3(NB * 8), dim3(256), 0, stream>>>(h0, W0T, T0buf[0]);

  // pipeline: step s runs jvp2(s-1) || jvp1(s) || t0(s+1)
  // sample offset of chunk c is c*NB; row stride 1024 elems; out2 1 fl/sample
  for (int s = 0; s <= nchunk; ++s) {
    const int c2 = s - 1, c1 = s, c0 = s + 1;
    const int n2 = (c2 >= 0 && c2 < nchunk) ? NB : 0;
    const int n1 = (c1 < nchunk) ? NB : 0;
    const int nt = (c0 < nchunk) ? NB * 8 : 0;
    if (n2 + n1 + nt == 0) continue;
    const int c2c = (c2 >= 0) ? c2 : 0;
    const int c1c = (c1 < nchunk) ? c1 : 0;
    const int c0c = (c0 < nchunk) ? c0 : 0;
    const bf* T1p = T1buf[c2c & 1];
    const bf* h2p = h2 + (size_t)c2c * NB * 1024;
    float* o2p    = out2 + (size_t)c2c * NB;
    const bf* T0c = T0buf[c1c & 1];
    const bf* h1c = h1 + (size_t)c1c * NB * 1024;
    bf* T1c = T1buf[c1c & 1];
    const bf* h0n = h0 + (size_t)c0c * NB * 1024;
    bf* T0n = T0buf[c0c & 1];
    jvp_step_k<<<dim3(n2 + n1 + nt), dim3(256), 0, stream>>>(
        T1p, h2p, o2p, T0c, h1c, T1c, h0n, T0n,
        W1b, W2b, W3b, W0T, n2, n1);
  }
}